// Round 5
// baseline (283.576 us; speedup 1.0000x reference)
//
#include <hip/hip_runtime.h>
#include <hip/hip_cooperative_groups.h>
#include <cstdint>
#include <cstddef>

namespace cg = cooperative_groups;

// ---------- types ----------
typedef __bf16 bf16x8 __attribute__((ext_vector_type(8)));
typedef float  f32x4  __attribute__((ext_vector_type(4)));

__device__ __forceinline__ unsigned short f2bf(float f) {
    union { __bf16 b; unsigned short u; } cv; cv.b = (__bf16)f; return cv.u;
}
__device__ __forceinline__ int iclamp(int v, int lo, int hi) {
    return v < lo ? lo : (v > hi ? hi : v);
}

// async global->LDS, 16B per lane. lds dst must be WAVE-UNIFORM base; HW adds lane*16.
__device__ __forceinline__ void gload16(const void* gsrc, void* ldsdst) {
    __builtin_amdgcn_global_load_lds(
        (const __attribute__((address_space(1))) unsigned int*)(uintptr_t)gsrc,
        (__attribute__((address_space(3))) unsigned int*)(uintptr_t)ldsdst,
        16, 0, 0);
}

#define MFMA16(a, b, c) __builtin_amdgcn_mfma_f32_16x16x32_bf16((a), (b), (c), 0, 0, 0)

#define QKV_BAR   __builtin_amdgcn_s_barrier()
#define QKV_SB0   __builtin_amdgcn_sched_barrier(0)
#define QKV_LGKM0 asm volatile("s_waitcnt lgkmcnt(0)" ::: "memory")
#define QKV_VM7   asm volatile("s_waitcnt vmcnt(7)" ::: "memory")
#define QKV_VM0   asm volatile("s_waitcnt vmcnt(0)" ::: "memory")
#define QKV_PRIO1 __builtin_amdgcn_s_setprio(1)
#define QKV_PRIO0 __builtin_amdgcn_s_setprio(0)

#define PHASE_READS(AB, I0)                                                    \
    af00 = *(const bf16x8*)((AB) + aRow + (I0) * 1024 + sw0);                  \
    af01 = *(const bf16x8*)((AB) + aRow + (I0) * 1024 + sw1);                  \
    af10 = *(const bf16x8*)((AB) + aRow + (I0) * 1024 + 1024 + sw0);           \
    af11 = *(const bf16x8*)((AB) + aRow + (I0) * 1024 + 1024 + sw1);

#define PHASE_MFMA(I0)                                                         \
    acc[(I0)][0]     = MFMA16(af00, b00, acc[(I0)][0]);                        \
    acc[(I0)][0]     = MFMA16(af01, b10, acc[(I0)][0]);                        \
    acc[(I0)][1]     = MFMA16(af00, b01, acc[(I0)][1]);                        \
    acc[(I0)][1]     = MFMA16(af01, b11, acc[(I0)][1]);                        \
    acc[(I0)][2]     = MFMA16(af00, b02, acc[(I0)][2]);                        \
    acc[(I0)][2]     = MFMA16(af01, b12, acc[(I0)][2]);                        \
    acc[(I0) + 1][0] = MFMA16(af10, b00, acc[(I0) + 1][0]);                    \
    acc[(I0) + 1][0] = MFMA16(af11, b10, acc[(I0) + 1][0]);                    \
    acc[(I0) + 1][1] = MFMA16(af10, b01, acc[(I0) + 1][1]);                    \
    acc[(I0) + 1][1] = MFMA16(af11, b11, acc[(I0) + 1][1]);                    \
    acc[(I0) + 1][2] = MFMA16(af10, b02, acc[(I0) + 1][2]);                    \
    acc[(I0) + 1][2] = MFMA16(af11, b12, acc[(I0) + 1][2]);

#define STAGE_T(BOA, BOB, KT) do {                                             \
    gload16(gA0 + (KT), lA0 + (BOA)); gload16(gA1 + (KT), lA1 + (BOA));        \
    gload16(gA2 + (KT), lA2 + (BOA)); gload16(gA3 + (KT), lA3 + (BOA));        \
    gload16(gB0 + (KT), lB0 + (BOB)); gload16(gB1 + (KT), lB1 + (BOB));        \
    gload16(gB2 + (KT), lB2 + (BOB)); } while (0)

#define KTILE(AB, BB, BOA, BOB, T) do {                                        \
    bf16x8 af00, af01, af10, af11;                                             \
    bf16x8 b00, b10, b01, b11, b02, b12;                                       \
    b00 = *(const bf16x8*)((BB) + bRow + sw0);                                 \
    b10 = *(const bf16x8*)((BB) + bRow + sw1);                                 \
    b01 = *(const bf16x8*)((BB) + bRow + 1024 + sw0);                          \
    b11 = *(const bf16x8*)((BB) + bRow + 1024 + sw1);                          \
    b02 = *(const bf16x8*)((BB) + bRow + 2048 + sw0);                          \
    b12 = *(const bf16x8*)((BB) + bRow + 2048 + sw1);                          \
    PHASE_READS(AB, 0);                                                        \
    QKV_BAR; QKV_LGKM0; QKV_SB0;                                               \
    QKV_PRIO1; PHASE_MFMA(0); QKV_PRIO0; QKV_BAR;                              \
    PHASE_READS(AB, 2);                                                        \
    QKV_BAR; QKV_LGKM0; QKV_SB0;                                               \
    QKV_PRIO1; PHASE_MFMA(2); QKV_PRIO0; QKV_BAR;                              \
    PHASE_READS(AB, 4);                                                        \
    QKV_BAR; QKV_LGKM0; QKV_SB0;                                               \
    QKV_PRIO1; PHASE_MFMA(4); QKV_PRIO0; QKV_BAR;                              \
    PHASE_READS(AB, 6);                                                        \
    QKV_LGKM0; QKV_SB0; QKV_BAR;                                               \
    if ((T) < 14) STAGE_T((BOA), (BOB), (T) * 64 + 128);                       \
    QKV_PRIO1; PHASE_MFMA(6); QKV_PRIO0;                                       \
    if ((T) < 14)      { QKV_VM7; QKV_SB0; QKV_BAR; }                          \
    else if ((T) < 15) { QKV_VM0; QKV_SB0; QKV_BAR; }                          \
} while (0)

// ================= FUSED single cooperative kernel =================
// 256 blocks x 512 threads, 1 block/CU (112 KB LDS). 4 phases + 3 grid syncs.
__global__ __launch_bounds__(512, 2) void fused_all(
        const float* __restrict__ x,  const float* __restrict__ Wq,
        const float* __restrict__ Wk, const float* __restrict__ Wv,
        const float* __restrict__ Wo, const float* __restrict__ bq,
        const float* __restrict__ bk, const float* __restrict__ bv,
        const float* __restrict__ bo, float* __restrict__ out,
        unsigned short* __restrict__ us) {
    __shared__ __align__(16) char LDSU[114688];   // 112 KB, overlaid per phase
    const int bx = blockIdx.x, tid = threadIdx.x;
    const int wave = tid >> 6, lane = tid & 63;
    const int lq = lane & 15, quad = lane >> 4;
    const int grp = tid >> 8, ltid = tid & 255;

    const size_t MEG = 1048576;
    unsigned short* xb = us;
    unsigned short* Wt = us + 4 * MEG;
    unsigned short* Qb = us + 8 * MEG;
    unsigned short* Kb = us + 12 * MEG;
    unsigned short* Vt = us + 16 * MEG;
    unsigned short* AO = us + 20 * MEG;
    float* bcat = (float*)(us + 24 * MEG);

    // ---------- phase 1: prep (3084 virtual blocks over 256x2 groups, 7 iters) ----------
    {
        float (*tile)[65] = (float(*)[65])(LDSU + grp * 16640);
        for (int it = 0; it < 7; ++it) {
            const int vb = bx * 2 + grp + it * 512;
            int z = 0, t = 0, n0 = 0, k0 = 0;
            bool isW = false;
            if (vb < 1024) {
                isW = true;
                z = vb >> 8; t = vb & 255;
                n0 = (t & 15) * 64; k0 = (t >> 4) * 64;
                const float* W = (z == 0) ? Wq : (z == 1) ? Wk : (z == 2) ? Wv : Wo;
                const int tr = ltid >> 4, tc = (ltid & 15) * 4;
#pragma unroll
                for (int i = 0; i < 4; ++i) {
                    int r = tr + i * 16;
                    float4 v = *(const float4*)(W + (size_t)(k0 + r) * 1024 + n0 + tc);
                    tile[r][tc + 0] = v.x; tile[r][tc + 1] = v.y;
                    tile[r][tc + 2] = v.z; tile[r][tc + 3] = v.w;
                }
            } else if (vb < 3072) {
                size_t i = ((size_t)(vb - 1024) * 256 + ltid) * 8;
                float4 a = *(const float4*)(x + i);
                float4 b2 = *(const float4*)(x + i + 4);
                union { unsigned short u[8]; uint4 q; } pk;
                pk.u[0] = f2bf(a.x);  pk.u[1] = f2bf(a.y);
                pk.u[2] = f2bf(a.z);  pk.u[3] = f2bf(a.w);
                pk.u[4] = f2bf(b2.x); pk.u[5] = f2bf(b2.y);
                pk.u[6] = f2bf(b2.z); pk.u[7] = f2bf(b2.w);
                *(uint4*)(xb + i) = pk.q;
            } else if (vb < 3084) {
                int i = (vb - 3072) * 256 + ltid;
                bcat[i] = (i < 1024) ? bq[i] : (i < 2048) ? bk[i - 1024] : bv[i - 2048];
            }
            __syncthreads();
            if (isW) {
                const int n = ltid & 63, kc = (ltid >> 6) * 16;
                union { unsigned short u[16]; uint4 q[2]; } pk;
#pragma unroll
                for (int c = 0; c < 16; ++c) pk.u[c] = f2bf(tile[kc + c][n]);
                uint4* dst = (uint4*)(Wt + (size_t)z * 1048576 + (size_t)(n0 + n) * 1024 + k0 + kc);
                dst[0] = pk.q[0]; dst[1] = pk.q[1];
            }
            __syncthreads();
        }
    }
    cg::this_grid().sync();

    // ---------- phase 2: QKV GEMM (verbatim 256x192, 4-phase counted vmcnt) ----------
    {
        unsigned short* Asm = (unsigned short*)LDSU;            // 64 KB (buf0/buf1)
        unsigned short* Bsm = (unsigned short*)(LDSU + 65536);  // 48 KB
        const int wr = wave >> 2, wc = wave & 3;
        const int m0 = (bx >> 4) * 256;
        const int n0 = ((bx & 7) * 2 + ((bx >> 3) & 1)) * 192;  // XCD-clustered n-panels

        f32x4 acc[8][3];
#pragma unroll
        for (int i = 0; i < 8; ++i)
#pragma unroll
            for (int j = 0; j < 3; ++j) acc[i][j] = f32x4{0.f, 0.f, 0.f, 0.f};

        float bi[3];
#pragma unroll
        for (int j = 0; j < 3; ++j) bi[j] = bcat[n0 + wc * 48 + j * 16 + lq];

        const int r8 = lane >> 3, cs = lane & 7;
        const int gch = (cs ^ r8) * 8;
        const unsigned short* gA0 = xb + (size_t)(m0 +   0 + wave * 8 + r8) * 1024 + gch;
        const unsigned short* gA1 = xb + (size_t)(m0 +  64 + wave * 8 + r8) * 1024 + gch;
        const unsigned short* gA2 = xb + (size_t)(m0 + 128 + wave * 8 + r8) * 1024 + gch;
        const unsigned short* gA3 = xb + (size_t)(m0 + 192 + wave * 8 + r8) * 1024 + gch;
        const unsigned short* gB0 = Wt + (size_t)(n0 +   0 + wave * 8 + r8) * 1024 + gch;
        const unsigned short* gB1 = Wt + (size_t)(n0 +  64 + wave * 8 + r8) * 1024 + gch;
        const unsigned short* gB2 = Wt + (size_t)(n0 + 128 + wave * 8 + r8) * 1024 + gch;
        unsigned short* lA0 = Asm + (  0 + wave * 8) * 64;
        unsigned short* lA1 = Asm + ( 64 + wave * 8) * 64;
        unsigned short* lA2 = Asm + (128 + wave * 8) * 64;
        unsigned short* lA3 = Asm + (192 + wave * 8) * 64;
        unsigned short* lB0 = Bsm + (  0 + wave * 8) * 64;
        unsigned short* lB1 = Bsm + ( 64 + wave * 8) * 64;
        unsigned short* lB2 = Bsm + (128 + wave * 8) * 64;

        const int sw0 = ((quad)     ^ (lq & 7)) * 8;
        const int sw1 = ((4 + quad) ^ (lq & 7)) * 8;
        const int aRow = (wr * 128 + lq) * 64;
        const int bRow = (wc * 48  + lq) * 64;

        STAGE_T(0, 0, 0);
        STAGE_T(16384, 12288, 64);
        QKV_VM7; QKV_SB0; QKV_BAR;

        for (int u = 0; u < 8; ++u) {
            const int t0 = u * 2;
            KTILE(Asm,         Bsm,         0,     0,     t0);
            KTILE(Asm + 16384, Bsm + 12288, 16384, 12288, t0 + 1);
        }

        const int b = m0 >> 11;
        const int mb = (m0 & 2047) + wr * 128;
        unsigned short* sw = Asm + wave * 1024;
        const int row32 = lane >> 1, half = lane & 1;
#pragma unroll
        for (int i = 0; i < 8; ++i) {
#pragma unroll
            for (int j = 0; j < 3; ++j)
#pragma unroll
                for (int r = 0; r < 4; ++r)
                    sw[(quad * 4 + r) * 56 + j * 16 + lq] = f2bf(acc[i][j][r] + bi[j]);
            const int sb = mb + i * 16;
#pragma unroll
            for (int j = 0; j < 3; ++j) {
                const int c0 = n0 + wc * 48 + j * 16;
                const int p = c0 >> 10, ch = c0 & 1023;
                const int h = ch >> 6, d0 = ch & 63;
                if (p < 2) {
                    unsigned short* base = (p == 0) ? Qb : Kb;
                    if (lane < 32) {
                        uint4 v = *(const uint4*)(sw + row32 * 56 + j * 16 + half * 8);
                        *(uint4*)(base + ((size_t)((b * 16 + h) * 2048 + sb + row32)) * 64
                                  + d0 + half * 8) = v;
                    }
                } else {
                    if (lane < 32) {
                        union { unsigned short u[8]; uint4 q; } pk;
#pragma unroll
                        for (int q2 = 0; q2 < 8; ++q2)
                            pk.u[q2] = sw[(half * 8 + q2) * 56 + j * 16 + row32];
                        *(uint4*)(Vt + ((size_t)((b * 16 + h) * 64 + d0 + row32)) * 2048
                                  + sb + half * 8) = pk.q;
                    }
                }
            }
        }
    }
    cg::this_grid().sync();

    // ---------- phase 3: sliding-window attention (4096 wave-tasks, 2 per wave) ----------
    {
        unsigned short* pw = ((unsigned short*)LDSU) + wave * (16 * 168);  // 8 x 5376 B
        for (int rep = 0; rep < 2; ++rep) {
            const int task = bx * 8 + wave + rep * 2048;
            const int b = task >> 11, h = (task >> 7) & 15, qt = task & 127;
            const int q0 = qt * 16;
            const bool edge = (qt < 4) || (qt >= 124);
            const unsigned short* Qh = Qb + (size_t)((b * 16 + h) * 2048) * 64;
            const unsigned short* Kh = Kb + (size_t)((b * 16 + h) * 2048) * 64;
            const unsigned short* Vh = Vt + (size_t)((b * 16 + h) * 64) * 2048;

            {
                unsigned int* zp = (unsigned int*)(pw + (lane >> 2) * 168 + 144 + (lane & 3) * 4);
                zp[0] = 0u; zp[1] = 0u;
            }

            const bf16x8 qa0 = *(const bf16x8*)(Qh + (size_t)(q0 + lq) * 64 + quad * 8);
            const bf16x8 qa1 = *(const bf16x8*)(Qh + (size_t)(q0 + lq) * 64 + 32 + quad * 8);

            float pr[9][4];
            float ls[4] = {0.f, 0.f, 0.f, 0.f};
#pragma unroll
            for (int t = 0; t < 9; ++t) {
                const int krow = q0 - 64 + t * 16 + lq;
                const bool need_mask = (t == 0) || (t == 8) || edge;
                const int krc = need_mask ? iclamp(krow, 0, 2047) : krow;
                const unsigned short* kp = Kh + (size_t)krc * 64 + quad * 8;
                const bf16x8 kf0 = *(const bf16x8*)kp;
                const bf16x8 kf1 = *(const bf16x8*)(kp + 32);
                f32x4 cacc = f32x4{0.f, 0.f, 0.f, 0.f};
                cacc = MFMA16(qa0, kf0, cacc);
                cacc = MFMA16(qa1, kf1, cacc);
                if (need_mask) {
#pragma unroll
                    for (int r = 0; r < 4; ++r) {
                        const int q = q0 + quad * 4 + r;
                        const int dj = q - krow;
                        const bool ok = (krow >= 0) && (krow < 2048) && (dj <= 64) && (dj >= -64);
                        const float pv = ok ? __expf(cacc[r] * 0.125f) : 0.f;
                        pr[t][r] = pv;
                        ls[r] += pv;
                    }
                } else {
#pragma unroll
                    for (int r = 0; r < 4; ++r) {
                        const float pv = __expf(cacc[r] * 0.125f);
                        pr[t][r] = pv;
                        ls[r] += pv;
                    }
                }
            }
#pragma unroll
            for (int r = 0; r < 4; ++r) {
#pragma unroll
                for (int off = 1; off < 16; off <<= 1)
                    ls[r] += __shfl_xor(ls[r], off);
            }
            float rinv[4];
#pragma unroll
            for (int r = 0; r < 4; ++r) rinv[r] = 1.f / ls[r];

#pragma unroll
            for (int t = 0; t < 9; ++t)
#pragma unroll
                for (int r = 0; r < 4; ++r)
                    pw[(quad * 4 + r) * 168 + t * 16 + lq] = f2bf(pr[t][r]);

            f32x4 oa[4];
#pragma unroll
            for (int dt = 0; dt < 4; ++dt) oa[dt] = f32x4{0.f, 0.f, 0.f, 0.f};
#pragma unroll
            for (int ks = 0; ks < 5; ++ks) {
                const bf16x8 pf = *(const bf16x8*)(pw + lq * 168 + ks * 32 + quad * 8);
                int s0 = q0 - 64 + ks * 32 + quad * 8;
                s0 = iclamp(s0, 0, 2040);
#pragma unroll
                for (int dt = 0; dt < 4; ++dt) {
                    const bf16x8 vf = *(const bf16x8*)(Vh + (size_t)(dt * 16 + lq) * 2048 + s0);
                    oa[dt] = MFMA16(pf, vf, oa[dt]);
                }
            }

#pragma unroll
            for (int dt = 0; dt < 4; ++dt)
#pragma unroll
                for (int r = 0; r < 4; ++r)
                    pw[(quad * 4 + r) * 72 + dt * 16 + lq] = f2bf(oa[dt][r] * rinv[r]);
            {
                const int row = lane >> 2, c0 = (lane & 3) * 16;
                uint4 v0 = *(const uint4*)(pw + row * 72 + c0);
                uint4 v1 = *(const uint4*)(pw + row * 72 + c0 + 8);
                unsigned short* dp = AO + (size_t)(b * 2048 + q0 + row) * 1024 + h * 64 + c0;
                *(uint4*)(dp) = v0;
                *(uint4*)(dp + 8) = v1;
            }
        }
    }
    cg::this_grid().sync();

    // ---------- phase 4: output projection (512 virtual blocks, 2 groups of 256) ----------
    {
        unsigned short* AsmO = (unsigned short*)(LDSU + grp * 24576);  // 16 KB
        unsigned short* BsmO = AsmO + 128 * 64;                        // + 8 KB
        const unsigned short* Wot = Wt + 3 * MEG;
        const int wv = wave & 3;
        const int vb = bx * 2 + grp;
        const int m0 = (vb >> 4) * 128, n0 = (vb & 15) * 64;

        f32x4 acc[4][2];
#pragma unroll
        for (int i = 0; i < 4; ++i)
#pragma unroll
            for (int j = 0; j < 2; ++j) acc[i][j] = f32x4{0.f, 0.f, 0.f, 0.f};

        float bi[2];
#pragma unroll
        for (int j = 0; j < 2; ++j) bi[j] = bo[n0 + (wv & 1) * 32 + j * 16 + lq];

        const int r8 = lane >> 3, cs = lane & 7;
        const int gch = (cs ^ r8) * 8;
        const unsigned short* gA[4];
        unsigned short* lA[4];
#pragma unroll
        for (int s = 0; s < 4; ++s) {
            const int r = wv * 32 + s * 8 + r8;
            gA[s] = AO + (size_t)(m0 + r) * 1024 + gch;
            lA[s] = AsmO + (wv * 32 + s * 8) * 64;
        }
        const unsigned short* gB[2];
        unsigned short* lB[2];
#pragma unroll
        for (int s = 0; s < 2; ++s) {
            const int r = wv * 16 + s * 8 + r8;
            gB[s] = Wot + (size_t)(n0 + r) * 1024 + gch;
            lB[s] = BsmO + (wv * 16 + s * 8) * 64;
        }

        int offA[4][2], offB[2][2];
#pragma unroll
        for (int kk = 0; kk < 2; ++kk) {
#pragma unroll
            for (int i = 0; i < 4; ++i) {
                const int rA = (wv >> 1) * 64 + i * 16 + lq;
                offA[i][kk] = rA * 64 + (((kk * 4 + quad) ^ (lq & 7)) * 8);
            }
#pragma unroll
            for (int j = 0; j < 2; ++j) {
                const int rB = (wv & 1) * 32 + j * 16 + lq;
                offB[j][kk] = rB * 64 + (((kk * 4 + quad) ^ (lq & 7)) * 8);
            }
        }

        for (int kt = 0; kt < 1024; kt += 64) {
#pragma unroll
            for (int s = 0; s < 4; ++s) gload16(gA[s] + kt, lA[s]);
#pragma unroll
            for (int s = 0; s < 2; ++s) gload16(gB[s] + kt, lB[s]);
            __syncthreads();
#pragma unroll
            for (int kk = 0; kk < 2; ++kk) {
                bf16x8 af[4], bfr[2];
#pragma unroll
                for (int i = 0; i < 4; ++i) af[i] = *(const bf16x8*)(AsmO + offA[i][kk]);
#pragma unroll
                for (int j = 0; j < 2; ++j) bfr[j] = *(const bf16x8*)(BsmO + offB[j][kk]);
#pragma unroll
                for (int i = 0; i < 4; ++i)
#pragma unroll
                    for (int j = 0; j < 2; ++j)
                        acc[i][j] = MFMA16(af[i], bfr[j], acc[i][j]);
            }
            __syncthreads();
        }

        float* swf = (float*)AsmO + wv * 528;
        const int row = lane >> 2, c0 = (lane & 3) * 8;
        const size_t obase = (size_t)(m0 + (wv >> 1) * 64) * 1024 + n0 + (wv & 1) * 32;
#pragma unroll
        for (int i = 0; i < 4; ++i) {
#pragma unroll
            for (int j = 0; j < 2; ++j)
#pragma unroll
                for (int r = 0; r < 4; ++r)
                    swf[(quad * 4 + r) * 33 + j * 16 + lq] = acc[i][j][r] + bi[j];
            float4 v0, v1;
            v0.x = swf[row * 33 + c0 + 0]; v0.y = swf[row * 33 + c0 + 1];
            v0.z = swf[row * 33 + c0 + 2]; v0.w = swf[row * 33 + c0 + 3];
            v1.x = swf[row * 33 + c0 + 4]; v1.y = swf[row * 33 + c0 + 5];
            v1.z = swf[row * 33 + c0 + 6]; v1.w = swf[row * 33 + c0 + 7];
            float* op = out + obase + (size_t)(i * 16 + row) * 1024 + c0;
            *(float4*)(op) = v0;
            *(float4*)(op + 4) = v1;
        }
    }
}

// ================= fallback: original 4-kernel pipeline =================
__global__ __launch_bounds__(256) void prep_k(const float* __restrict__ x,
                                              const float* __restrict__ Wq,
                                              const float* __restrict__ Wk,
                                              const float* __restrict__ Wv,
                                              const float* __restrict__ Wo,
                                              const float* __restrict__ bq,
                                              const float* __restrict__ bk,
                                              const float* __restrict__ bv,
                                              unsigned short* __restrict__ xb,
                                              unsigned short* __restrict__ Wt,
                                              float* __restrict__ bc) {
    __shared__ float tile[64][65];
    const int bx = blockIdx.x, tid = threadIdx.x;
    if (bx < 1024) {
        const int z = bx >> 8, t = bx & 255;
        const float* W = (z == 0) ? Wq : (z == 1) ? Wk : (z == 2) ? Wv : Wo;
        const int n0 = (t & 15) * 64, k0 = (t >> 4) * 64;
        const int tr = tid >> 4, tc = (tid & 15) * 4;
#pragma unroll
        for (int i = 0; i < 4; ++i) {
            int r = tr + i * 16;
            float4 v = *(const float4*)(W + (size_t)(k0 + r) * 1024 + n0 + tc);
            tile[r][tc + 0] = v.x; tile[r][tc + 1] = v.y;
            tile[r][tc + 2] = v.z; tile[r][tc + 3] = v.w;
        }
        __syncthreads();
        const int n = tid & 63, kc = (tid >> 6) * 16;
        union { unsigned short u[16]; uint4 q[2]; } pk;
#pragma unroll
        for (int c = 0; c < 16; ++c) pk.u[c] = f2bf(tile[kc + c][n]);
        uint4* dst = (uint4*)(Wt + (size_t)z * 1048576 + (size_t)(n0 + n) * 1024 + k0 + kc);
        dst[0] = pk.q[0]; dst[1] = pk.q[1];
    } else if (bx < 3072) {
        size_t i = ((size_t)(bx - 1024) * 256 + tid) * 8;
        float4 a = *(const float4*)(x + i);
        float4 b = *(const float4*)(x + i + 4);
        union { unsigned short u[8]; uint4 q; } pk;
        pk.u[0] = f2bf(a.x); pk.u[1] = f2bf(a.y); pk.u[2] = f2bf(a.z); pk.u[3] = f2bf(a.w);
        pk.u[4] = f2bf(b.x); pk.u[5] = f2bf(b.y); pk.u[6] = f2bf(b.z); pk.u[7] = f2bf(b.w);
        *(uint4*)(xb + i) = pk.q;
    } else {
        int i = (bx - 3072) * 256 + tid;
        bc[i] = (i < 1024) ? bq[i] : (i < 2048) ? bk[i - 1024] : bv[i - 2048];
    }
}

__global__ __launch_bounds__(512, 2) void gemm_qkv(const unsigned short* __restrict__ xb,
                                                   const unsigned short* __restrict__ Wt,
                                                   const float* __restrict__ bcat,
                                                   unsigned short* __restrict__ Qb,
                                                   unsigned short* __restrict__ Kb,
                                                   unsigned short* __restrict__ Vt) {
    __shared__ __align__(16) unsigned short Asm[2 * 256 * 64];
    __shared__ __align__(16) unsigned short Bsm[2 * 192 * 64];
    const int tid = threadIdx.x, wave = tid >> 6, lane = tid & 63;
    const int lq = lane & 15, quad = lane >> 4;
    const int wr = wave >> 2, wc = wave & 3;
    const int m0 = blockIdx.x * 256, n0 = blockIdx.y * 192;

    f32x4 acc[8][3];
#pragma unroll
    for (int i = 0; i < 8; ++i)
#pragma unroll
        for (int j = 0; j < 3; ++j) acc[i][j] = f32x4{0.f, 0.f, 0.f, 0.f};

    float bi[3];
#pragma unroll
    for (int j = 0; j < 3; ++j) bi[j] = bcat[n0 + wc * 48 + j * 16 + lq];

    const int r8 = lane >> 3, cs = lane & 7;
    const int gch = (cs ^ r8) * 8;
    const unsigned short* gA0 = xb + (size_t)(m0 +   0 + wave * 8 + r8) * 1024 + gch;
    const unsigned short* gA1 = xb + (size_t)(m0 +  64 + wave * 8 + r8) * 1024 + gch;
    const unsigned short* gA2 = xb + (size_t)(m0 + 128 + wave * 8 + r8) * 1024 + gch;
    const unsigned short* gA3 = xb + (size_t)(m0 + 192 + wave * 8 + r8) * 1024 + gch;
    const unsigned short* gB0 = Wt + (size_t)(n0 +   0 + wave * 8 + r8) * 1024 + gch;
    const unsigned short* gB1 = Wt + (size_t)(n0 +  64 + wave * 8 + r8) * 1024 + gch;
    const unsigned short* gB2 = Wt + (size_t)(n0 + 128 + wave * 8 + r8) * 1024 + gch;
    unsigned short* lA0 = Asm + (  0 + wave * 8) * 64;
    unsigned short* lA1 = Asm + ( 64 + wave * 8) * 64;
    unsigned short* lA2 = Asm + (128 + wave * 8) * 64;
    unsigned short* lA3 = Asm + (192 + wave * 8) * 64;
    unsigned short* lB0 = Bsm + (  0 + wave * 8) * 64;
    unsigned short* lB1 = Bsm + ( 64 + wave * 8) * 64;
    unsigned short* lB2 = Bsm + (128 + wave * 8) * 64;

    const int sw0 = ((quad)     ^ (lq & 7)) * 8;
    const int sw1 = ((4 + quad) ^ (lq & 7)) * 8;
    const int aRow = (wr * 128 + lq) * 64;
    const int bRow = (wc * 48  + lq) * 64;

    STAGE_T(0, 0, 0);
    STAGE_T(16384, 12288, 64);
    QKV_VM7; QKV_SB0; QKV_BAR;

    for (int u = 0; u < 8; ++u) {
        const int t0 = u * 2;
        KTILE(Asm,          Bsm,          0,     0,     t0);
        KTILE(Asm + 16384,  Bsm + 12288,  16384, 12288, t0 + 1);
    }

    const int b = m0 >> 11;
    const int mb = (m0 & 2047) + wr * 128;
    unsigned short* sw = Asm + wave * 1024;
    const int row32 = lane >> 1, half = lane & 1;
#pragma unroll
    for (int i = 0; i < 8; ++i) {
#pragma unroll
        for (int j = 0; j < 3; ++j)
#pragma unroll
            for (int r = 0; r < 4; ++r)
                sw[(quad * 4 + r) * 56 + j * 16 + lq] = f2bf(acc[i][j][r] + bi[j]);
        const int sb = mb + i * 16;
#pragma unroll
        for (int j = 0; j < 3; ++j) {
            const int c0 = n0 + wc * 48 + j * 16;
            const int p = c0 >> 10, ch = c0 & 1023;
            const int h = ch >> 6, d0 = ch & 63;
            if (p < 2) {
                unsigned short* base = (p == 0) ? Qb : Kb;
                if (lane < 32) {
                    uint4 v = *(const uint4*)(sw + row32 * 56 + j * 16 + half * 8);
                    *(uint4*)(base + ((size_t)((b * 16 + h) * 2048 + sb + row32)) * 64
                              + d0 + half * 8) = v;
                }
            } else {
                if (lane < 32) {
                    union { unsigned short u[8]; uint4 q; } pk;
#pragma unroll
                    for (int q2 = 0; q2 < 8; ++q2)
                        pk.u[q2] = sw[(half * 8 + q2) * 56 + j * 16 + row32];
                    *(uint4*)(Vt + ((size_t)((b * 16 + h) * 64 + d0 + row32)) * 2048
                              + sb + half * 8) = pk.q;
                }
            }
        }
    }
}

__global__ __launch_bounds__(256, 4) void attn_k(const unsigned short* __restrict__ Qb,
                                                 const unsigned short* __restrict__ Kb,
                                                 const unsigned short* __restrict__ Vt,
                                                 unsigned short* __restrict__ AO) {
    __shared__ __align__(16) unsigned short P[4][16 * 168];
    const int tid = threadIdx.x, wave = tid >> 6, lane = tid & 63;
    const int lq = lane & 15, quad = lane >> 4;
    const int b = blockIdx.z, h = blockIdx.y;
    const int q0 = blockIdx.x * 64 + wave * 16;
    const bool edge = (blockIdx.x == 0) || (blockIdx.x == 31);
    const unsigned short* Qh = Qb + (size_t)((b * 16 + h) * 2048) * 64;
    const unsigned short* Kh = Kb + (size_t)((b * 16 + h) * 2048) * 64;
    const unsigned short* Vh = Vt + (size_t)((b * 16 + h) * 64) * 2048;
    unsigned short* pw = P[wave];

    {
        unsigned int* zp = (unsigned int*)(pw + (lane >> 2) * 168 + 144 + (lane & 3) * 4);
        zp[0] = 0u; zp[1] = 0u;
    }

    const bf16x8 qa0 = *(const bf16x8*)(Qh + (size_t)(q0 + lq) * 64 + quad * 8);
    const bf16x8 qa1 = *(const bf16x8*)(Qh + (size_t)(q0 + lq) * 64 + 32 + quad * 8);

    float pr[9][4];
    float ls[4] = {0.f, 0.f, 0.f, 0.f};
#pragma unroll
    for (int t = 0; t < 9; ++t) {
        const int krow = q0 - 64 + t * 16 + lq;
        const bool need_mask = (t == 0) || (t == 8) || edge;
        const int krc = need_mask ? iclamp(krow, 0, 2047) : krow;
        const unsigned short* kp = Kh + (size_t)krc * 64 + quad * 8;
        const bf16x8 kf0 = *(const bf16x8*)kp;
        const bf16x8 kf1 = *(const bf16x8*)(kp + 32);
        f32x4 cacc = f32x4{0.f, 0.f, 0.f, 0.f};
        cacc = MFMA16(qa0, kf0, cacc);
        cacc = MFMA16(qa1, kf1, cacc);
        if (need_mask) {
#pragma unroll
            for (int r = 0; r < 4; ++r) {
                const int q = q0 + quad * 4 + r;
                const int dj = q - krow;
                const bool ok = (krow >= 0) && (krow < 2048) && (dj <= 64) && (dj >= -64);
                const float pv = ok ? __expf(cacc[r] * 0.125f) : 0.f;
                pr[t][r] = pv;
                ls[r] += pv;
            }
        } else {
#pragma unroll
            for (int r = 0; r < 4; ++r) {
                const float pv = __expf(cacc[r] * 0.125f);
                pr[t][r] = pv;
                ls[r] += pv;
            }
        }
    }
#pragma unroll
    for (int r = 0; r < 4; ++r) {
#pragma unroll
        for (int off = 1; off < 16; off <<= 1)
            ls[r] += __shfl_xor(ls[r], off);
    }
    float rinv[4];
#pragma unroll
    for (int r = 0; r < 4; ++r) rinv[r] = 1.f / ls[r];

#pragma unroll
    for (int t = 0; t < 9; ++t)
#pragma unroll
        for (int r = 0; r < 4; ++r)
            pw[(quad * 4 + r) * 168 + t * 16 + lq] = f2bf(pr[t][r]);

    f32x4 oa[4];
#pragma unroll
    for (int dt = 0; dt < 4; ++dt) oa[dt] = f32x4{0.f, 0.f, 0.f, 0.f};
#pragma unroll
    for (int ks = 0; ks < 5; ++ks) {
        const bf16x8 pf = *(const bf16x8*)(pw + lq * 168 + ks * 32 + quad * 8);
        int s0 = q0 - 64 + ks * 32 + quad * 8;
        s0 = iclamp(s0, 0, 2040);
#pragma unroll
        for (int dt = 0; dt < 4; ++dt) {
            const bf16x8 vf = *(const bf16x8*)(Vh + (size_t)(dt * 16 + lq) * 2048 + s0);
            oa[dt] = MFMA16(pf, vf, oa[dt]);
        }
    }

#pragma unroll
    for (int dt = 0; dt < 4; ++dt)
#pragma unroll
        for (int r = 0; r < 4; ++r)
            pw[(quad * 4 + r) * 72 + dt * 16 + lq] = f2bf(oa[dt][r] * rinv[r]);
    {
        const int row = lane >> 2, c0 = (lane & 3) * 16;
        uint4 v0 = *(const uint4*)(pw + row * 72 + c0);
        uint4 v1 = *(const uint4*)(pw + row * 72 + c0 + 8);
        unsigned short* dp = AO + (size_t)(b * 2048 + q0 + row) * 1024 + h * 64 + c0;
        *(uint4*)(dp) = v0;
        *(uint4*)(dp + 8) = v1;
    }
}

__global__ __launch_bounds__(256, 2) void gemm_out(const unsigned short* __restrict__ AO,
                                                   const unsigned short* __restrict__ Wot,
                                                   const float* __restrict__ bo,
                                                   float* __restrict__ out) {
    __shared__ __align__(16) unsigned short Asm[128 * 64];
    __shared__ __align__(16) unsigned short Bsm[64 * 64];
    const int tid = threadIdx.x, wave = tid >> 6, lane = tid & 63;
    const int lq = lane & 15, quad = lane >> 4;
    const int m0 = blockIdx.y * 128, n0 = blockIdx.x * 64;

    f32x4 acc[4][2];
#pragma unroll
    for (int i = 0; i < 4; ++i)
#pragma unroll
        for (int j = 0; j < 2; ++j) acc[i][j] = f32x4{0.f, 0.f, 0.f, 0.f};

    float bi[2];
#pragma unroll
    for (int j = 0; j < 2; ++j) bi[j] = bo[n0 + (wave & 1) * 32 + j * 16 + lq];

    const int r8 = lane >> 3, cs = lane & 7;
    const int gch = (cs ^ r8) * 8;
    const unsigned short* gA[4];
    unsigned short* lA[4];
#pragma unroll
    for (int s = 0; s < 4; ++s) {
        const int r = wave * 32 + s * 8 + r8;
        gA[s] = AO + (size_t)(m0 + r) * 1024 + gch;
        lA[s] = Asm + (wave * 32 + s * 8) * 64;
    }
    const unsigned short* gB[2];
    unsigned short* lB[2];
#pragma unroll
    for (int s = 0; s < 2; ++s) {
        const int r = wave * 16 + s * 8 + r8;
        gB[s] = Wot + (size_t)(n0 + r) * 1024 + gch;
        lB[s] = Bsm + (wave * 16 + s * 8) * 64;
    }

    int offA[4][2], offB[2][2];
#pragma unroll
    for (int kk = 0; kk < 2; ++kk) {
#pragma unroll
        for (int i = 0; i < 4; ++i) {
            const int rA = (wave >> 1) * 64 + i * 16 + lq;
            offA[i][kk] = rA * 64 + (((kk * 4 + quad) ^ (lq & 7)) * 8);
        }
#pragma unroll
        for (int j = 0; j < 2; ++j) {
            const int rB = (wave & 1) * 32 + j * 16 + lq;
            offB[j][kk] = rB * 64 + (((kk * 4 + quad) ^ (lq & 7)) * 8);
        }
    }

    for (int kt = 0; kt < 1024; kt += 64) {
#pragma unroll
        for (int s = 0; s < 4; ++s) gload16(gA[s] + kt, lA[s]);
#pragma unroll
        for (int s = 0; s < 2; ++s) gload16(gB[s] + kt, lB[s]);
        __syncthreads();
#pragma unroll
        for (int kk = 0; kk < 2; ++kk) {
            bf16x8 af[4], bfr[2];
#pragma unroll
            for (int i = 0; i < 4; ++i) af[i] = *(const bf16x8*)(Asm + offA[i][kk]);
#pragma unroll
            for (int j = 0; j < 2; ++j) bfr[j] = *(const bf16x8*)(Bsm + offB[j][kk]);
#pragma unroll
            for (int i = 0; i < 4; ++i)
#pragma unroll
                for (int j = 0; j < 2; ++j)
                    acc[i][j] = MFMA16(af[i], bfr[j], acc[i][j]);
        }
        __syncthreads();
    }

    float* swf = (float*)Asm + wave * 528;
    const int row = lane >> 2, c0 = (lane & 3) * 8;
    const size_t obase = (size_t)(m0 + (wave >> 1) * 64) * 1024 + n0 + (wave & 1) * 32;
#pragma unroll
    for (int i = 0; i < 4; ++i) {
#pragma unroll
        for (int j = 0; j < 2; ++j)
#pragma unroll
            for (int r = 0; r < 4; ++r)
                swf[(quad * 4 + r) * 33 + j * 16 + lq] = acc[i][j][r] + bi[j];
        float4 v0, v1;
        v0.x = swf[row * 33 + c0 + 0]; v0.y = swf[row * 33 + c0 + 1];
        v0.z = swf[row * 33 + c0 + 2]; v0.w = swf[row * 33 + c0 + 3];
        v1.x = swf[row * 33 + c0 + 4]; v1.y = swf[row * 33 + c0 + 5];
        v1.z = swf[row * 33 + c0 + 6]; v1.w = swf[row * 33 + c0 + 7];
        float* op = out + obase + (size_t)(i * 16 + row) * 1024 + c0;
        *(float4*)(op) = v0;
        *(float4*)(op + 4) = v1;
    }
}

// ---------- host ----------
extern "C" void kernel_launch(void* const* d_in, const int* in_sizes, int n_in,
                              void* d_out, int out_size, void* d_ws, size_t ws_size,
                              hipStream_t stream) {
    const float* x  = (const float*)d_in[0];
    const float* Wq = (const float*)d_in[1];
    const float* bq = (const float*)d_in[2];
    const float* Wk = (const float*)d_in[3];
    const float* bk = (const float*)d_in[4];
    const float* Wv = (const float*)d_in[5];
    const float* bv = (const float*)d_in[6];
    const float* Wo = (const float*)d_in[7];
    const float* bo = (const float*)d_in[8];
    float* out = (float*)d_out;
    unsigned short* us = (unsigned short*)d_ws;

    void* args[11];
    args[0] = (void*)&x;  args[1] = (void*)&Wq; args[2] = (void*)&Wk;
    args[3] = (void*)&Wv; args[4] = (void*)&Wo; args[5] = (void*)&bq;
    args[6] = (void*)&bk; args[7] = (void*)&bv; args[8] = (void*)&bo;
    args[9] = (void*)&out; args[10] = (void*)&us;

    hipError_t e = hipLaunchCooperativeKernel((const void*)fused_all, dim3(256), dim3(512),
                                              args, 0, stream);
    if (e != hipSuccess) {
        // fallback: original 4-kernel pipeline
        const size_t MEG = 1048576;
        unsigned short* xb = us;
        unsigned short* Wt = us + 4 * MEG;
        unsigned short* Qb = us + 8 * MEG;
        unsigned short* Kb = us + 12 * MEG;
        unsigned short* Vt = us + 16 * MEG;
        unsigned short* AO = us + 20 * MEG;
        float* bcat = (float*)(us + 24 * MEG);
        prep_k<<<3084, 256, 0, stream>>>(x, Wq, Wk, Wv, Wo, bq, bk, bv, xb, Wt, bcat);
        gemm_qkv<<<dim3(16, 16), 512, 0, stream>>>(xb, Wt, bcat, Qb, Kb, Vt);
        attn_k<<<dim3(32, 16, 2), 256, 0, stream>>>(Qb, Kb, Vt, AO);
        gemm_out<<<dim3(16, 32), 256, 0, stream>>>(AO, Wt + 3 * MEG, bo, out);
    }
}

// Round 12
// 160.173 us; speedup vs baseline: 1.7704x; 1.7704x over previous
//
#include <hip/hip_runtime.h>
#include <cstdint>
#include <cstddef>

// ---------- types ----------
typedef __bf16 bf16x8 __attribute__((ext_vector_type(8)));
typedef float  f32x4  __attribute__((ext_vector_type(4)));

__device__ __forceinline__ unsigned short f2bf(float f) {
    union { __bf16 b; unsigned short u; } cv; cv.b = (__bf16)f; return cv.u;
}
__device__ __forceinline__ int iclamp(int v, int lo, int hi) {
    return v < lo ? lo : (v > hi ? hi : v);
}

// async global->LDS, 16B per lane. lds dst must be WAVE-UNIFORM base; HW adds lane*16.
__device__ __forceinline__ void gload16(const void* gsrc, void* ldsdst) {
    __builtin_amdgcn_global_load_lds(
        (const __attribute__((address_space(1))) unsigned int*)(uintptr_t)gsrc,
        (__attribute__((address_space(3))) unsigned int*)(uintptr_t)ldsdst,
        16, 0, 0);
}

#define MFMA16(a, b, c) __builtin_amdgcn_mfma_f32_16x16x32_bf16((a), (b), (c), 0, 0, 0)

// ---------- kernel 1: fused prep — weight transpose+cast | x cast | bias concat ----------
__global__ __launch_bounds__(256) void prep_k(const float* __restrict__ x,
                                              const float* __restrict__ Wq,
                                              const float* __restrict__ Wk,
                                              const float* __restrict__ Wv,
                                              const float* __restrict__ Wo,
                                              const float* __restrict__ bq,
                                              const float* __restrict__ bk,
                                              const float* __restrict__ bv,
                                              unsigned short* __restrict__ xb,
                                              unsigned short* __restrict__ Wt,
                                              float* __restrict__ bc) {
    __shared__ float tile[64][65];
    const int bx = blockIdx.x, tid = threadIdx.x;
    if (bx < 1024) {
        const int z = bx >> 8, t = bx & 255;
        const float* W = (z == 0) ? Wq : (z == 1) ? Wk : (z == 2) ? Wv : Wo;
        const int n0 = (t & 15) * 64, k0 = (t >> 4) * 64;
        const int tr = tid >> 4, tc = (tid & 15) * 4;
#pragma unroll
        for (int i = 0; i < 4; ++i) {
            int r = tr + i * 16;
            float4 v = *(const float4*)(W + (size_t)(k0 + r) * 1024 + n0 + tc);
            tile[r][tc + 0] = v.x; tile[r][tc + 1] = v.y;
            tile[r][tc + 2] = v.z; tile[r][tc + 3] = v.w;
        }
        __syncthreads();
        const int n = tid & 63, kc = (tid >> 6) * 16;
        union { unsigned short u[16]; uint4 q[2]; } pk;
#pragma unroll
        for (int c = 0; c < 16; ++c) pk.u[c] = f2bf(tile[kc + c][n]);
        uint4* dst = (uint4*)(Wt + (size_t)z * 1048576 + (size_t)(n0 + n) * 1024 + k0 + kc);
        dst[0] = pk.q[0]; dst[1] = pk.q[1];
    } else if (bx < 3072) {
        size_t i = ((size_t)(bx - 1024) * 256 + tid) * 8;
        float4 a = *(const float4*)(x + i);
        float4 b = *(const float4*)(x + i + 4);
        union { unsigned short u[8]; uint4 q; } pk;
        pk.u[0] = f2bf(a.x); pk.u[1] = f2bf(a.y); pk.u[2] = f2bf(a.z); pk.u[3] = f2bf(a.w);
        pk.u[4] = f2bf(b.x); pk.u[5] = f2bf(b.y); pk.u[6] = f2bf(b.z); pk.u[7] = f2bf(b.w);
        *(uint4*)(xb + i) = pk.q;
    } else {
        int i = (bx - 3072) * 256 + tid;
        bc[i] = (i < 1024) ? bq[i] : (i < 2048) ? bk[i - 1024] : bv[i - 2048];
    }
}

// ---------- shared schedule macros (counted-vmcnt pipeline) ----------
#define QKV_BAR   __builtin_amdgcn_s_barrier()
#define QKV_SB0   __builtin_amdgcn_sched_barrier(0)
#define QKV_LGKM0 asm volatile("s_waitcnt lgkmcnt(0)" ::: "memory")
#define QKV_VM7   asm volatile("s_waitcnt vmcnt(7)" ::: "memory")
#define QKV_VM4   asm volatile("s_waitcnt vmcnt(4)" ::: "memory")
#define QKV_VM0   asm volatile("s_waitcnt vmcnt(0)" ::: "memory")
#define QKV_PRIO1 __builtin_amdgcn_s_setprio(1)
#define QKV_PRIO0 __builtin_amdgcn_s_setprio(0)

#define PHASE_READS(AB, I0)                                                    \
    af00 = *(const bf16x8*)((AB) + aRow + (I0) * 1024 + sw0);                  \
    af01 = *(const bf16x8*)((AB) + aRow + (I0) * 1024 + sw1);                  \
    af10 = *(const bf16x8*)((AB) + aRow + (I0) * 1024 + 1024 + sw0);           \
    af11 = *(const bf16x8*)((AB) + aRow + (I0) * 1024 + 1024 + sw1);

#define PHASE_MFMA(I0)                                                         \
    acc[(I0)][0]     = MFMA16(af00, b00, acc[(I0)][0]);                        \
    acc[(I0)][0]     = MFMA16(af01, b10, acc[(I0)][0]);                        \
    acc[(I0)][1]     = MFMA16(af00, b01, acc[(I0)][1]);                        \
    acc[(I0)][1]     = MFMA16(af01, b11, acc[(I0)][1]);                        \
    acc[(I0)][2]     = MFMA16(af00, b02, acc[(I0)][2]);                        \
    acc[(I0)][2]     = MFMA16(af01, b12, acc[(I0)][2]);                        \
    acc[(I0) + 1][0] = MFMA16(af10, b00, acc[(I0) + 1][0]);                    \
    acc[(I0) + 1][0] = MFMA16(af11, b10, acc[(I0) + 1][0]);                    \
    acc[(I0) + 1][1] = MFMA16(af10, b01, acc[(I0) + 1][1]);                    \
    acc[(I0) + 1][1] = MFMA16(af11, b11, acc[(I0) + 1][1]);                    \
    acc[(I0) + 1][2] = MFMA16(af10, b02, acc[(I0) + 1][2]);                    \
    acc[(I0) + 1][2] = MFMA16(af11, b12, acc[(I0) + 1][2]);

#define STAGE_T(BOA, BOB, KT) do {                                             \
    gload16(gA0 + (KT), lA0 + (BOA)); gload16(gA1 + (KT), lA1 + (BOA));        \
    gload16(gA2 + (KT), lA2 + (BOA)); gload16(gA3 + (KT), lA3 + (BOA));        \
    gload16(gB0 + (KT), lB0 + (BOB)); gload16(gB1 + (KT), lB1 + (BOB));        \
    gload16(gB2 + (KT), lB2 + (BOB)); } while (0)

#define KTILE(AB, BB, BOA, BOB, T) do {                                        \
    bf16x8 af00, af01, af10, af11;                                             \
    bf16x8 b00, b10, b01, b11, b02, b12;                                       \
    b00 = *(const bf16x8*)((BB) + bRow + sw0);                                 \
    b10 = *(const bf16x8*)((BB) + bRow + sw1);                                 \
    b01 = *(const bf16x8*)((BB) + bRow + 1024 + sw0);                          \
    b11 = *(const bf16x8*)((BB) + bRow + 1024 + sw1);                          \
    b02 = *(const bf16x8*)((BB) + bRow + 2048 + sw0);                          \
    b12 = *(const bf16x8*)((BB) + bRow + 2048 + sw1);                          \
    PHASE_READS(AB, 0);                                                        \
    QKV_BAR; QKV_LGKM0; QKV_SB0;                                               \
    QKV_PRIO1; PHASE_MFMA(0); QKV_PRIO0; QKV_BAR;                              \
    PHASE_READS(AB, 2);                                                        \
    QKV_BAR; QKV_LGKM0; QKV_SB0;                                               \
    QKV_PRIO1; PHASE_MFMA(2); QKV_PRIO0; QKV_BAR;                              \
    PHASE_READS(AB, 4);                                                        \
    QKV_BAR; QKV_LGKM0; QKV_SB0;                                               \
    QKV_PRIO1; PHASE_MFMA(4); QKV_PRIO0; QKV_BAR;                              \
    PHASE_READS(AB, 6);                                                        \
    QKV_LGKM0; QKV_SB0; QKV_BAR;                                               \
    if ((T) < 14) STAGE_T((BOA), (BOB), (T) * 64 + 128);                       \
    QKV_PRIO1; PHASE_MFMA(6); QKV_PRIO0;                                       \
    if ((T) < 14)      { QKV_VM7; QKV_SB0; QKV_BAR; }                          \
    else if ((T) < 15) { QKV_VM0; QKV_SB0; QKV_BAR; }                          \
} while (0)

// ---------- kernel 2: fused QKV GEMM (M=4096, N=3072, K=1024) ----------
__global__ __launch_bounds__(512, 2) void gemm_qkv(const unsigned short* __restrict__ xb,
                                                   const unsigned short* __restrict__ Wt,
                                                   const float* __restrict__ bcat,
                                                   unsigned short* __restrict__ Qb,
                                                   unsigned short* __restrict__ Kb,
                                                   unsigned short* __restrict__ Vt) {
    __shared__ __align__(16) unsigned short Asm[2 * 256 * 64];  // 64 KB
    __shared__ __align__(16) unsigned short Bsm[2 * 192 * 64];  // 48 KB
    const int tid = threadIdx.x, wave = tid >> 6, lane = tid & 63;
    const int lq = lane & 15, quad = lane >> 4;
    const int wr = wave >> 2, wc = wave & 3;
    const int m0 = blockIdx.x * 256, n0 = blockIdx.y * 192;

    f32x4 acc[8][3];
#pragma unroll
    for (int i = 0; i < 8; ++i)
#pragma unroll
        for (int j = 0; j < 3; ++j) acc[i][j] = f32x4{0.f, 0.f, 0.f, 0.f};

    float bi[3];
#pragma unroll
    for (int j = 0; j < 3; ++j) bi[j] = bcat[n0 + wc * 48 + j * 16 + lq];

    const int r8 = lane >> 3, cs = lane & 7;
    const int gch = (cs ^ r8) * 8;
    const unsigned short* gA0 = xb + (size_t)(m0 +   0 + wave * 8 + r8) * 1024 + gch;
    const unsigned short* gA1 = xb + (size_t)(m0 +  64 + wave * 8 + r8) * 1024 + gch;
    const unsigned short* gA2 = xb + (size_t)(m0 + 128 + wave * 8 + r8) * 1024 + gch;
    const unsigned short* gA3 = xb + (size_t)(m0 + 192 + wave * 8 + r8) * 1024 + gch;
    const unsigned short* gB0 = Wt + (size_t)(n0 +   0 + wave * 8 + r8) * 1024 + gch;
    const unsigned short* gB1 = Wt + (size_t)(n0 +  64 + wave * 8 + r8) * 1024 + gch;
    const unsigned short* gB2 = Wt + (size_t)(n0 + 128 + wave * 8 + r8) * 1024 + gch;
    unsigned short* lA0 = Asm + (  0 + wave * 8) * 64;
    unsigned short* lA1 = Asm + ( 64 + wave * 8) * 64;
    unsigned short* lA2 = Asm + (128 + wave * 8) * 64;
    unsigned short* lA3 = Asm + (192 + wave * 8) * 64;
    unsigned short* lB0 = Bsm + (  0 + wave * 8) * 64;
    unsigned short* lB1 = Bsm + ( 64 + wave * 8) * 64;
    unsigned short* lB2 = Bsm + (128 + wave * 8) * 64;

    const int sw0 = ((quad)     ^ (lq & 7)) * 8;
    const int sw1 = ((4 + quad) ^ (lq & 7)) * 8;
    const int aRow = (wr * 128 + lq) * 64;
    const int bRow = (wc * 48  + lq) * 64;

    STAGE_T(0, 0, 0);
    STAGE_T(16384, 12288, 64);
    QKV_VM7; QKV_SB0; QKV_BAR;

    for (int u = 0; u < 8; ++u) {
        const int t0 = u * 2;
        KTILE(Asm,          Bsm,          0,     0,     t0);
        KTILE(Asm + 16384,  Bsm + 12288,  16384, 12288, t0 + 1);
    }

    const int b = m0 >> 11;
    const int mb = (m0 & 2047) + wr * 128;
    unsigned short* sw = Asm + wave * 1024;
    const int row32 = lane >> 1, half = lane & 1;
#pragma unroll
    for (int i = 0; i < 8; ++i) {
#pragma unroll
        for (int j = 0; j < 3; ++j)
#pragma unroll
            for (int r = 0; r < 4; ++r)
                sw[(quad * 4 + r) * 56 + j * 16 + lq] = f2bf(acc[i][j][r] + bi[j]);
        const int sb = mb + i * 16;
#pragma unroll
        for (int j = 0; j < 3; ++j) {
            const int c0 = n0 + wc * 48 + j * 16;
            const int p = c0 >> 10, ch = c0 & 1023;
            const int h = ch >> 6, d0 = ch & 63;
            if (p < 2) {
                unsigned short* base = (p == 0) ? Qb : Kb;
                if (lane < 32) {
                    uint4 v = *(const uint4*)(sw + row32 * 56 + j * 16 + half * 8);
                    *(uint4*)(base + ((size_t)((b * 16 + h) * 2048 + sb + row32)) * 64
                              + d0 + half * 8) = v;
                }
            } else {
                if (lane < 32) {
                    union { unsigned short u[8]; uint4 q; } pk;
#pragma unroll
                    for (int q2 = 0; q2 < 8; ++q2)
                        pk.u[q2] = sw[(half * 8 + q2) * 56 + j * 16 + row32];
                    *(uint4*)(Vt + ((size_t)((b * 16 + h) * 64 + d0 + row32)) * 2048
                              + sb + half * 8) = pk.q;
                }
            }
        }
    }
}

// ---------- kernel 3: sliding-window attention, one wave per 16-row Q-tile ----------
__global__ __launch_bounds__(256, 4) void attn_k(const unsigned short* __restrict__ Qb,
                                                 const unsigned short* __restrict__ Kb,
                                                 const unsigned short* __restrict__ Vt,
                                                 unsigned short* __restrict__ AO) {
    __shared__ __align__(16) unsigned short P[4][16 * 168];
    const int tid = threadIdx.x, wave = tid >> 6, lane = tid & 63;
    const int lq = lane & 15, quad = lane >> 4;
    const int b = blockIdx.z, h = blockIdx.y;
    const int q0 = blockIdx.x * 64 + wave * 16;
    const bool edge = (blockIdx.x == 0) || (blockIdx.x == 31);
    const unsigned short* Qh = Qb + (size_t)((b * 16 + h) * 2048) * 64;
    const unsigned short* Kh = Kb + (size_t)((b * 16 + h) * 2048) * 64;
    const unsigned short* Vh = Vt + (size_t)((b * 16 + h) * 64) * 2048;
    unsigned short* pw = P[wave];

    {
        unsigned int* zp = (unsigned int*)(pw + (lane >> 2) * 168 + 144 + (lane & 3) * 4);
        zp[0] = 0u; zp[1] = 0u;
    }

    const bf16x8 qa0 = *(const bf16x8*)(Qh + (size_t)(q0 + lq) * 64 + quad * 8);
    const bf16x8 qa1 = *(const bf16x8*)(Qh + (size_t)(q0 + lq) * 64 + 32 + quad * 8);

    float pr[9][4];
    float ls[4] = {0.f, 0.f, 0.f, 0.f};
#pragma unroll
    for (int t = 0; t < 9; ++t) {
        const int krow = q0 - 64 + t * 16 + lq;
        const bool need_mask = (t == 0) || (t == 8) || edge;
        const int krc = need_mask ? iclamp(krow, 0, 2047) : krow;
        const unsigned short* kp = Kh + (size_t)krc * 64 + quad * 8;
        const bf16x8 kf0 = *(const bf16x8*)kp;
        const bf16x8 kf1 = *(const bf16x8*)(kp + 32);
        f32x4 cacc = f32x4{0.f, 0.f, 0.f, 0.f};
        cacc = MFMA16(qa0, kf0, cacc);
        cacc = MFMA16(qa1, kf1, cacc);
        if (need_mask) {
#pragma unroll
            for (int r = 0; r < 4; ++r) {
                const int q = q0 + quad * 4 + r;
                const int dj = q - krow;
                const bool ok = (krow >= 0) && (krow < 2048) && (dj <= 64) && (dj >= -64);
                const float pv = ok ? __expf(cacc[r] * 0.125f) : 0.f;
                pr[t][r] = pv;
                ls[r] += pv;
            }
        } else {
#pragma unroll
            for (int r = 0; r < 4; ++r) {
                const float pv = __expf(cacc[r] * 0.125f);
                pr[t][r] = pv;
                ls[r] += pv;
            }
        }
    }
#pragma unroll
    for (int r = 0; r < 4; ++r) {
#pragma unroll
        for (int off = 1; off < 16; off <<= 1)
            ls[r] += __shfl_xor(ls[r], off);
    }
    float rinv[4];
#pragma unroll
    for (int r = 0; r < 4; ++r) rinv[r] = 1.f / ls[r];

#pragma unroll
    for (int t = 0; t < 9; ++t)
#pragma unroll
        for (int r = 0; r < 4; ++r)
            pw[(quad * 4 + r) * 168 + t * 16 + lq] = f2bf(pr[t][r]);

    f32x4 oa[4];
#pragma unroll
    for (int dt = 0; dt < 4; ++dt) oa[dt] = f32x4{0.f, 0.f, 0.f, 0.f};
#pragma unroll
    for (int ks = 0; ks < 5; ++ks) {
        const bf16x8 pf = *(const bf16x8*)(pw + lq * 168 + ks * 32 + quad * 8);
        int s0 = q0 - 64 + ks * 32 + quad * 8;
        s0 = iclamp(s0, 0, 2040);
#pragma unroll
        for (int dt = 0; dt < 4; ++dt) {
            const bf16x8 vf = *(const bf16x8*)(Vh + (size_t)(dt * 16 + lq) * 2048 + s0);
            oa[dt] = MFMA16(pf, vf, oa[dt]);
        }
    }

#pragma unroll
    for (int dt = 0; dt < 4; ++dt)
#pragma unroll
        for (int r = 0; r < 4; ++r)
            pw[(quad * 4 + r) * 72 + dt * 16 + lq] = f2bf(oa[dt][r] * rinv[r]);
    {
        const int row = lane >> 2, c0 = (lane & 3) * 16;
        uint4 v0 = *(const uint4*)(pw + row * 72 + c0);
        uint4 v1 = *(const uint4*)(pw + row * 72 + c0 + 8);
        unsigned short* dp = AO + (size_t)(b * 2048 + q0 + row) * 1024 + h * 64 + c0;
        *(uint4*)(dp) = v0;
        *(uint4*)(dp + 8) = v1;
    }
}

// ---------- kernel 4: output projection (M=4096, N=1024, K=1024) ----------
// 128x128 tile, 8 waves (2M x 4N), grid 8x32 = 256 blocks = 1/CU.
// Same counted-vmcnt schedule as gemm_qkv: 2 phases/K-tile, depth-2 prefetch,
// vmcnt(4) (one 4-load tile in flight across boundaries), setprio around MFMA.
// LDS: A 2x128x64 (32KB) + B 2x128x64 (32KB) = 64 KB.

#define STAGE_O(BO, KT) do {                                                   \
    gload16(gAo0 + (KT), lAo0 + (BO)); gload16(gAo1 + (KT), lAo1 + (BO));      \
    gload16(gBo0 + (KT), lBo0 + (BO)); gload16(gBo1 + (KT), lBo1 + (BO)); } while (0)

#define KTILE_O(AB, BB, BO, T) do {                                            \
    bf16x8 a00, a01, a10, a11, b00, b10, b01, b11;                             \
    b00 = *(const bf16x8*)((BB) + bRow + sw0);                                 \
    b10 = *(const bf16x8*)((BB) + bRow + sw1);                                 \
    b01 = *(const bf16x8*)((BB) + bRow + 1024 + sw0);                          \
    b11 = *(const bf16x8*)((BB) + bRow + 1024 + sw1);                          \
    a00 = *(const bf16x8*)((AB) + aRow + sw0);                                 \
    a01 = *(const bf16x8*)((AB) + aRow + sw1);                                 \
    a10 = *(const bf16x8*)((AB) + aRow + 1024 + sw0);                          \
    a11 = *(const bf16x8*)((AB) + aRow + 1024 + sw1);                          \
    QKV_BAR; QKV_LGKM0; QKV_SB0;                                               \
    QKV_PRIO1;                                                                 \
    acc[0][0]=MFMA16(a00,b00,acc[0][0]); acc[0][0]=MFMA16(a01,b10,acc[0][0]);  \
    acc[0][1]=MFMA16(a00,b01,acc[0][1]); acc[0][1]=MFMA16(a01,b11,acc[0][1]);  \
    acc[1][0]=MFMA16(a10,b00,acc[1][0]); acc[1][0]=MFMA16(a11,b10,acc[1][0]);  \
    acc[1][1]=MFMA16(a10,b01,acc[1][1]); acc[1][1]=MFMA16(a11,b11,acc[1][1]);  \
    QKV_PRIO0; QKV_BAR;                                                        \
    a00 = *(const bf16x8*)((AB) + aRow + 2048 + sw0);                          \
    a01 = *(const bf16x8*)((AB) + aRow + 2048 + sw1);                          \
    a10 = *(const bf16x8*)((AB) + aRow + 3072 + sw0);                          \
    a11 = *(const bf16x8*)((AB) + aRow + 3072 + sw1);                          \
    QKV_LGKM0; QKV_SB0; QKV_BAR;                                               \
    if ((T) < 14) STAGE_O((BO), (T) * 64 + 128);                               \
    QKV_PRIO1;                                                                 \
    acc[2][0]=MFMA16(a00,b00,acc[2][0]); acc[2][0]=MFMA16(a01,b10,acc[2][0]);  \
    acc[2][1]=MFMA16(a00,b01,acc[2][1]); acc[2][1]=MFMA16(a01,b11,acc[2][1]);  \
    acc[3][0]=MFMA16(a10,b00,acc[3][0]); acc[3][0]=MFMA16(a11,b10,acc[3][0]);  \
    acc[3][1]=MFMA16(a10,b01,acc[3][1]); acc[3][1]=MFMA16(a11,b11,acc[3][1]);  \
    QKV_PRIO0;                                                                 \
    if ((T) < 14)      { QKV_VM4; QKV_SB0; QKV_BAR; }                          \
    else if ((T) < 15) { QKV_VM0; QKV_SB0; QKV_BAR; }                          \
} while (0)

__global__ __launch_bounds__(512, 2) void gemm_out(const unsigned short* __restrict__ AO,
                                                   const unsigned short* __restrict__ Wot,
                                                   const float* __restrict__ bo,
                                                   float* __restrict__ out) {
    __shared__ __align__(16) unsigned short Asm[2 * 128 * 64];  // 32 KB
    __shared__ __align__(16) unsigned short Bsm[2 * 128 * 64];  // 32 KB
    const int tid = threadIdx.x, wave = tid >> 6, lane = tid & 63;
    const int lq = lane & 15, quad = lane >> 4;
    const int wr = wave >> 2, wc = wave & 3;
    const int m0 = blockIdx.y * 128, n0 = blockIdx.x * 128;

    f32x4 acc[4][2];
#pragma unroll
    for (int i = 0; i < 4; ++i)
#pragma unroll
        for (int j = 0; j < 2; ++j) acc[i][j] = f32x4{0.f, 0.f, 0.f, 0.f};

    float bi[2];
#pragma unroll
    for (int j = 0; j < 2; ++j) bi[j] = bo[n0 + wc * 32 + j * 16 + lq];

    const int r8 = lane >> 3, cs = lane & 7;
    const int gch = (cs ^ r8) * 8;
    const unsigned short* gAo0 = AO  + (size_t)(m0 +  0 + wave * 8 + r8) * 1024 + gch;
    const unsigned short* gAo1 = AO  + (size_t)(m0 + 64 + wave * 8 + r8) * 1024 + gch;
    const unsigned short* gBo0 = Wot + (size_t)(n0 +  0 + wave * 8 + r8) * 1024 + gch;
    const unsigned short* gBo1 = Wot + (size_t)(n0 + 64 + wave * 8 + r8) * 1024 + gch;
    unsigned short* lAo0 = Asm + ( 0 + wave * 8) * 64;
    unsigned short* lAo1 = Asm + (64 + wave * 8) * 64;
    unsigned short* lBo0 = Bsm + ( 0 + wave * 8) * 64;
    unsigned short* lBo1 = Bsm + (64 + wave * 8) * 64;

    const int sw0 = ((quad)     ^ (lq & 7)) * 8;
    const int sw1 = ((4 + quad) ^ (lq & 7)) * 8;
    const int aRow = (wr * 64 + lq) * 64;
    const int bRow = (wc * 32 + lq) * 64;

    // prologue: stage tiles 0 and 1; wait tile 0 (4 of tile 1 stay in flight)
    STAGE_O(0, 0);
    STAGE_O(8192, 64);
    QKV_VM4; QKV_SB0; QKV_BAR;

    for (int u = 0; u < 8; ++u) {
        const int t0 = u * 2;
        KTILE_O(Asm,        Bsm,        0,    t0);
        KTILE_O(Asm + 8192, Bsm + 8192, 8192, t0 + 1);
    }

    // epilogue: barrier (wave7's bounce region crosses into buf1), then
    // f32 stride-33 LDS bounce -> 2x global_store_dwordx4 per lane per i-tile
    __syncthreads();
    float* swf = (float*)Asm + wave * 528;     // 16 rows x 33 f32 per wave
    const int row = lane >> 2, c0 = (lane & 3) * 8;
    const size_t obase = (size_t)(m0 + wr * 64) * 1024 + n0 + wc * 32;
#pragma unroll
    for (int i = 0; i < 4; ++i) {
#pragma unroll
        for (int j = 0; j < 2; ++j)
#pragma unroll
            for (int r = 0; r < 4; ++r)
                swf[(quad * 4 + r) * 33 + j * 16 + lq] = acc[i][j][r] + bi[j];
        float4 v0, v1;
        v0.x = swf[row * 33 + c0 + 0]; v0.y = swf[row * 33 + c0 + 1];
        v0.z = swf[row * 33 + c0 + 2]; v0.w = swf[row * 33 + c0 + 3];
        v1.x = swf[row * 33 + c0 + 4]; v1.y = swf[row * 33 + c0 + 5];
        v1.z = swf[row * 33 + c0 + 6]; v1.w = swf[row * 33 + c0 + 7];
        float* op = out + obase + (size_t)(i * 16 + row) * 1024 + c0;
        *(float4*)(op) = v0;
        *(float4*)(op + 4) = v1;
    }
}

// ---------- host ----------
extern "C" void kernel_launch(void* const* d_in, const int* in_sizes, int n_in,
                              void* d_out, int out_size, void* d_ws, size_t ws_size,
                              hipStream_t stream) {
    const float* x  = (const float*)d_in[0];
    const float* Wq = (const float*)d_in[1];
    const float* bq = (const float*)d_in[2];
    const float* Wk = (const float*)d_in[3];
    const float* bk = (const float*)d_in[4];
    const float* Wv = (const float*)d_in[5];
    const float* bv = (const float*)d_in[6];
    const float* Wo = (const float*)d_in[7];
    const float* bo = (const float*)d_in[8];
    float* out = (float*)d_out;

    unsigned short* us = (unsigned short*)d_ws;
    const size_t MEG = 1048576;
    unsigned short* xb = us;                 // 4M bf16: x cast
    unsigned short* Wt = us + 4 * MEG;       // 4x1M bf16: W^T for Q,K,V,O
    unsigned short* Qb = us + 8 * MEG;       // [b,h,s,d]
    unsigned short* Kb = us + 12 * MEG;      // [b,h,s,d]
    unsigned short* Vt = us + 16 * MEG;      // [b,h,d,s]
    unsigned short* AO = us + 20 * MEG;      // [b,s,h*d]
    float* bcat = (float*)(us + 24 * MEG);   // 3072 f32

    prep_k<<<3084, 256, 0, stream>>>(x, Wq, Wk, Wv, Wo, bq, bk, bv, xb, Wt, bcat);
    gemm_qkv<<<dim3(16, 16), 512, 0, stream>>>(xb, Wt, bcat, Qb, Kb, Vt);
    attn_k<<<dim3(32, 16, 2), 256, 0, stream>>>(Qb, Kb, Vt, AO);
    gemm_out<<<dim3(8, 32), 512, 0, stream>>>(AO, Wt + 3 * MEG, bo, out);
}

// Round 13
// 157.313 us; speedup vs baseline: 1.8026x; 1.0182x over previous
//
#include <hip/hip_runtime.h>
#include <cstdint>
#include <cstddef>

// ---------- types ----------
typedef __bf16 bf16x8 __attribute__((ext_vector_type(8)));
typedef float  f32x4  __attribute__((ext_vector_type(4)));

__device__ __forceinline__ unsigned short f2bf(float f) {
    union { __bf16 b; unsigned short u; } cv; cv.b = (__bf16)f; return cv.u;
}
__device__ __forceinline__ int iclamp(int v, int lo, int hi) {
    return v < lo ? lo : (v > hi ? hi : v);
}

// async global->LDS, 16B per lane. lds dst must be WAVE-UNIFORM base; HW adds lane*16.
__device__ __forceinline__ void gload16(const void* gsrc, void* ldsdst) {
    __builtin_amdgcn_global_load_lds(
        (const __attribute__((address_space(1))) unsigned int*)(uintptr_t)gsrc,
        (__attribute__((address_space(3))) unsigned int*)(uintptr_t)ldsdst,
        16, 0, 0);
}

#define MFMA16(a, b, c) __builtin_amdgcn_mfma_f32_16x16x32_bf16((a), (b), (c), 0, 0, 0)

// ---------- kernel 1: fused prep — weight transpose+cast | x cast | bias concat ----------
// W-transpose pack phase: n = tid>>2, kc = (tid&3)*16 -> 4 consecutive lanes write
// 128 B contiguous per output row (was 64 lanes x 32 B at 2-KB stride).
__global__ __launch_bounds__(256) void prep_k(const float* __restrict__ x,
                                              const float* __restrict__ Wq,
                                              const float* __restrict__ Wk,
                                              const float* __restrict__ Wv,
                                              const float* __restrict__ Wo,
                                              const float* __restrict__ bq,
                                              const float* __restrict__ bk,
                                              const float* __restrict__ bv,
                                              unsigned short* __restrict__ xb,
                                              unsigned short* __restrict__ Wt,
                                              float* __restrict__ bc) {
    __shared__ float tile[64][65];
    const int bx = blockIdx.x, tid = threadIdx.x;
    if (bx < 1024) {
        const int z = bx >> 8, t = bx & 255;
        const float* W = (z == 0) ? Wq : (z == 1) ? Wk : (z == 2) ? Wv : Wo;
        const int n0 = (t & 15) * 64, k0 = (t >> 4) * 64;
        const int tr = tid >> 4, tc = (tid & 15) * 4;
#pragma unroll
        for (int i = 0; i < 4; ++i) {
            int r = tr + i * 16;
            float4 v = *(const float4*)(W + (size_t)(k0 + r) * 1024 + n0 + tc);
            tile[r][tc + 0] = v.x; tile[r][tc + 1] = v.y;
            tile[r][tc + 2] = v.z; tile[r][tc + 3] = v.w;
        }
        __syncthreads();
        const int n = tid >> 2, kc = (tid & 3) * 16;
        union { unsigned short u[16]; uint4 q[2]; } pk;
#pragma unroll
        for (int c = 0; c < 16; ++c) pk.u[c] = f2bf(tile[kc + c][n]);
        uint4* dst = (uint4*)(Wt + (size_t)z * 1048576 + (size_t)(n0 + n) * 1024 + k0 + kc);
        dst[0] = pk.q[0]; dst[1] = pk.q[1];
    } else if (bx < 3072) {
        size_t i = ((size_t)(bx - 1024) * 256 + tid) * 8;
        float4 a = *(const float4*)(x + i);
        float4 b = *(const float4*)(x + i + 4);
        union { unsigned short u[8]; uint4 q; } pk;
        pk.u[0] = f2bf(a.x); pk.u[1] = f2bf(a.y); pk.u[2] = f2bf(a.z); pk.u[3] = f2bf(a.w);
        pk.u[4] = f2bf(b.x); pk.u[5] = f2bf(b.y); pk.u[6] = f2bf(b.z); pk.u[7] = f2bf(b.w);
        *(uint4*)(xb + i) = pk.q;
    } else {
        int i = (bx - 3072) * 256 + tid;
        bc[i] = (i < 1024) ? bq[i] : (i < 2048) ? bk[i - 1024] : bv[i - 2048];
    }
}

// ---------- shared schedule macros (counted-vmcnt pipeline) ----------
#define QKV_BAR   __builtin_amdgcn_s_barrier()
#define QKV_SB0   __builtin_amdgcn_sched_barrier(0)
#define QKV_LGKM0 asm volatile("s_waitcnt lgkmcnt(0)" ::: "memory")
#define QKV_VM7   asm volatile("s_waitcnt vmcnt(7)" ::: "memory")
#define QKV_VM4   asm volatile("s_waitcnt vmcnt(4)" ::: "memory")
#define QKV_VM0   asm volatile("s_waitcnt vmcnt(0)" ::: "memory")
#define QKV_PRIO1 __builtin_amdgcn_s_setprio(1)
#define QKV_PRIO0 __builtin_amdgcn_s_setprio(0)

#define PHASE_READS(AB, I0)                                                    \
    af00 = *(const bf16x8*)((AB) + aRow + (I0) * 1024 + sw0);                  \
    af01 = *(const bf16x8*)((AB) + aRow + (I0) * 1024 + sw1);                  \
    af10 = *(const bf16x8*)((AB) + aRow + (I0) * 1024 + 1024 + sw0);           \
    af11 = *(const bf16x8*)((AB) + aRow + (I0) * 1024 + 1024 + sw1);

#define PHASE_MFMA(I0)                                                         \
    acc[(I0)][0]     = MFMA16(af00, b00, acc[(I0)][0]);                        \
    acc[(I0)][0]     = MFMA16(af01, b10, acc[(I0)][0]);                        \
    acc[(I0)][1]     = MFMA16(af00, b01, acc[(I0)][1]);                        \
    acc[(I0)][1]     = MFMA16(af01, b11, acc[(I0)][1]);                        \
    acc[(I0)][2]     = MFMA16(af00, b02, acc[(I0)][2]);                        \
    acc[(I0)][2]     = MFMA16(af01, b12, acc[(I0)][2]);                        \
    acc[(I0) + 1][0] = MFMA16(af10, b00, acc[(I0) + 1][0]);                    \
    acc[(I0) + 1][0] = MFMA16(af11, b10, acc[(I0) + 1][0]);                    \
    acc[(I0) + 1][1] = MFMA16(af10, b01, acc[(I0) + 1][1]);                    \
    acc[(I0) + 1][1] = MFMA16(af11, b11, acc[(I0) + 1][1]);                    \
    acc[(I0) + 1][2] = MFMA16(af10, b02, acc[(I0) + 1][2]);                    \
    acc[(I0) + 1][2] = MFMA16(af11, b12, acc[(I0) + 1][2]);

#define STAGE_T(BOA, BOB, KT) do {                                             \
    gload16(gA0 + (KT), lA0 + (BOA)); gload16(gA1 + (KT), lA1 + (BOA));        \
    gload16(gA2 + (KT), lA2 + (BOA)); gload16(gA3 + (KT), lA3 + (BOA));        \
    gload16(gB0 + (KT), lB0 + (BOB)); gload16(gB1 + (KT), lB1 + (BOB));        \
    gload16(gB2 + (KT), lB2 + (BOB)); } while (0)

#define KTILE(AB, BB, BOA, BOB, T) do {                                        \
    bf16x8 af00, af01, af10, af11;                                             \
    bf16x8 b00, b10, b01, b11, b02, b12;                                       \
    b00 = *(const bf16x8*)((BB) + bRow + sw0);                                 \
    b10 = *(const bf16x8*)((BB) + bRow + sw1);                                 \
    b01 = *(const bf16x8*)((BB) + bRow + 1024 + sw0);                          \
    b11 = *(const bf16x8*)((BB) + bRow + 1024 + sw1);                          \
    b02 = *(const bf16x8*)((BB) + bRow + 2048 + sw0);                          \
    b12 = *(const bf16x8*)((BB) + bRow + 2048 + sw1);                          \
    PHASE_READS(AB, 0);                                                        \
    QKV_BAR; QKV_LGKM0; QKV_SB0;                                               \
    QKV_PRIO1; PHASE_MFMA(0); QKV_PRIO0; QKV_BAR;                              \
    PHASE_READS(AB, 2);                                                        \
    QKV_BAR; QKV_LGKM0; QKV_SB0;                                               \
    QKV_PRIO1; PHASE_MFMA(2); QKV_PRIO0; QKV_BAR;                              \
    PHASE_READS(AB, 4);                                                        \
    QKV_BAR; QKV_LGKM0; QKV_SB0;                                               \
    QKV_PRIO1; PHASE_MFMA(4); QKV_PRIO0; QKV_BAR;                              \
    PHASE_READS(AB, 6);                                                        \
    QKV_LGKM0; QKV_SB0; QKV_BAR;                                               \
    if ((T) < 14) STAGE_T((BOA), (BOB), (T) * 64 + 128);                       \
    QKV_PRIO1; PHASE_MFMA(6); QKV_PRIO0;                                       \
    if ((T) < 14)      { QKV_VM7; QKV_SB0; QKV_BAR; }                          \
    else if ((T) < 15) { QKV_VM0; QKV_SB0; QKV_BAR; }                          \
} while (0)

// ---------- kernel 2: fused QKV GEMM (M=4096, N=3072, K=1024) ----------
__global__ __launch_bounds__(512, 2) void gemm_qkv(const unsigned short* __restrict__ xb,
                                                   const unsigned short* __restrict__ Wt,
                                                   const float* __restrict__ bcat,
                                                   unsigned short* __restrict__ Qb,
                                                   unsigned short* __restrict__ Kb,
                                                   unsigned short* __restrict__ Vt) {
    __shared__ __align__(16) unsigned short Asm[2 * 256 * 64];  // 64 KB
    __shared__ __align__(16) unsigned short Bsm[2 * 192 * 64];  // 48 KB
    const int tid = threadIdx.x, wave = tid >> 6, lane = tid & 63;
    const int lq = lane & 15, quad = lane >> 4;
    const int wr = wave >> 2, wc = wave & 3;
    const int m0 = blockIdx.x * 256, n0 = blockIdx.y * 192;

    f32x4 acc[8][3];
#pragma unroll
    for (int i = 0; i < 8; ++i)
#pragma unroll
        for (int j = 0; j < 3; ++j) acc[i][j] = f32x4{0.f, 0.f, 0.f, 0.f};

    float bi[3];
#pragma unroll
    for (int j = 0; j < 3; ++j) bi[j] = bcat[n0 + wc * 48 + j * 16 + lq];

    const int r8 = lane >> 3, cs = lane & 7;
    const int gch = (cs ^ r8) * 8;
    const unsigned short* gA0 = xb + (size_t)(m0 +   0 + wave * 8 + r8) * 1024 + gch;
    const unsigned short* gA1 = xb + (size_t)(m0 +  64 + wave * 8 + r8) * 1024 + gch;
    const unsigned short* gA2 = xb + (size_t)(m0 + 128 + wave * 8 + r8) * 1024 + gch;
    const unsigned short* gA3 = xb + (size_t)(m0 + 192 + wave * 8 + r8) * 1024 + gch;
    const unsigned short* gB0 = Wt + (size_t)(n0 +   0 + wave * 8 + r8) * 1024 + gch;
    const unsigned short* gB1 = Wt + (size_t)(n0 +  64 + wave * 8 + r8) * 1024 + gch;
    const unsigned short* gB2 = Wt + (size_t)(n0 + 128 + wave * 8 + r8) * 1024 + gch;
    unsigned short* lA0 = Asm + (  0 + wave * 8) * 64;
    unsigned short* lA1 = Asm + ( 64 + wave * 8) * 64;
    unsigned short* lA2 = Asm + (128 + wave * 8) * 64;
    unsigned short* lA3 = Asm + (192 + wave * 8) * 64;
    unsigned short* lB0 = Bsm + (  0 + wave * 8) * 64;
    unsigned short* lB1 = Bsm + ( 64 + wave * 8) * 64;
    unsigned short* lB2 = Bsm + (128 + wave * 8) * 64;

    const int sw0 = ((quad)     ^ (lq & 7)) * 8;
    const int sw1 = ((4 + quad) ^ (lq & 7)) * 8;
    const int aRow = (wr * 128 + lq) * 64;
    const int bRow = (wc * 48  + lq) * 64;

    STAGE_T(0, 0, 0);
    STAGE_T(16384, 12288, 64);
    QKV_VM7; QKV_SB0; QKV_BAR;

    for (int u = 0; u < 8; ++u) {
        const int t0 = u * 2;
        KTILE(Asm,          Bsm,          0,     0,     t0);
        KTILE(Asm + 16384,  Bsm + 12288,  16384, 12288, t0 + 1);
    }

    const int b = m0 >> 11;
    const int mb = (m0 & 2047) + wr * 128;
    unsigned short* sw = Asm + wave * 1024;
    const int row32 = lane >> 1, half = lane & 1;
#pragma unroll
    for (int i = 0; i < 8; ++i) {
#pragma unroll
        for (int j = 0; j < 3; ++j)
#pragma unroll
            for (int r = 0; r < 4; ++r)
                sw[(quad * 4 + r) * 56 + j * 16 + lq] = f2bf(acc[i][j][r] + bi[j]);
        const int sb = mb + i * 16;
#pragma unroll
        for (int j = 0; j < 3; ++j) {
            const int c0 = n0 + wc * 48 + j * 16;
            const int p = c0 >> 10, ch = c0 & 1023;
            const int h = ch >> 6, d0 = ch & 63;
            if (p < 2) {
                unsigned short* base = (p == 0) ? Qb : Kb;
                if (lane < 32) {
                    uint4 v = *(const uint4*)(sw + row32 * 56 + j * 16 + half * 8);
                    *(uint4*)(base + ((size_t)((b * 16 + h) * 2048 + sb + row32)) * 64
                              + d0 + half * 8) = v;
                }
            } else {
                if (lane < 32) {
                    union { unsigned short u[8]; uint4 q; } pk;
#pragma unroll
                    for (int q2 = 0; q2 < 8; ++q2)
                        pk.u[q2] = sw[(half * 8 + q2) * 56 + j * 16 + row32];
                    *(uint4*)(Vt + ((size_t)((b * 16 + h) * 64 + d0 + row32)) * 2048
                              + sb + half * 8) = pk.q;
                }
            }
        }
    }
}

// ---------- kernel 3: sliding-window attention, one wave per 16-row Q-tile ----------
__global__ __launch_bounds__(256, 4) void attn_k(const unsigned short* __restrict__ Qb,
                                                 const unsigned short* __restrict__ Kb,
                                                 const unsigned short* __restrict__ Vt,
                                                 unsigned short* __restrict__ AO) {
    __shared__ __align__(16) unsigned short P[4][16 * 168];
    const int tid = threadIdx.x, wave = tid >> 6, lane = tid & 63;
    const int lq = lane & 15, quad = lane >> 4;
    const int b = blockIdx.z, h = blockIdx.y;
    const int q0 = blockIdx.x * 64 + wave * 16;
    const bool edge = (blockIdx.x == 0) || (blockIdx.x == 31);
    const unsigned short* Qh = Qb + (size_t)((b * 16 + h) * 2048) * 64;
    const unsigned short* Kh = Kb + (size_t)((b * 16 + h) * 2048) * 64;
    const unsigned short* Vh = Vt + (size_t)((b * 16 + h) * 64) * 2048;
    unsigned short* pw = P[wave];

    {
        unsigned int* zp = (unsigned int*)(pw + (lane >> 2) * 168 + 144 + (lane & 3) * 4);
        zp[0] = 0u; zp[1] = 0u;
    }

    const bf16x8 qa0 = *(const bf16x8*)(Qh + (size_t)(q0 + lq) * 64 + quad * 8);
    const bf16x8 qa1 = *(const bf16x8*)(Qh + (size_t)(q0 + lq) * 64 + 32 + quad * 8);

    float pr[9][4];
    float ls[4] = {0.f, 0.f, 0.f, 0.f};
#pragma unroll
    for (int t = 0; t < 9; ++t) {
        const int krow = q0 - 64 + t * 16 + lq;
        const bool need_mask = (t == 0) || (t == 8) || edge;
        const int krc = need_mask ? iclamp(krow, 0, 2047) : krow;
        const unsigned short* kp = Kh + (size_t)krc * 64 + quad * 8;
        const bf16x8 kf0 = *(const bf16x8*)kp;
        const bf16x8 kf1 = *(const bf16x8*)(kp + 32);
        f32x4 cacc = f32x4{0.f, 0.f, 0.f, 0.f};
        cacc = MFMA16(qa0, kf0, cacc);
        cacc = MFMA16(qa1, kf1, cacc);
        if (need_mask) {
#pragma unroll
            for (int r = 0; r < 4; ++r) {
                const int q = q0 + quad * 4 + r;
                const int dj = q - krow;
                const bool ok = (krow >= 0) && (krow < 2048) && (dj <= 64) && (dj >= -64);
                const float pv = ok ? __expf(cacc[r] * 0.125f) : 0.f;
                pr[t][r] = pv;
                ls[r] += pv;
            }
        } else {
#pragma unroll
            for (int r = 0; r < 4; ++r) {
                const float pv = __expf(cacc[r] * 0.125f);
                pr[t][r] = pv;
                ls[r] += pv;
            }
        }
    }
#pragma unroll
    for (int r = 0; r < 4; ++r) {
#pragma unroll
        for (int off = 1; off < 16; off <<= 1)
            ls[r] += __shfl_xor(ls[r], off);
    }
    float rinv[4];
#pragma unroll
    for (int r = 0; r < 4; ++r) rinv[r] = 1.f / ls[r];

#pragma unroll
    for (int t = 0; t < 9; ++t)
#pragma unroll
        for (int r = 0; r < 4; ++r)
            pw[(quad * 4 + r) * 168 + t * 16 + lq] = f2bf(pr[t][r]);

    f32x4 oa[4];
#pragma unroll
    for (int dt = 0; dt < 4; ++dt) oa[dt] = f32x4{0.f, 0.f, 0.f, 0.f};
#pragma unroll
    for (int ks = 0; ks < 5; ++ks) {
        const bf16x8 pf = *(const bf16x8*)(pw + lq * 168 + ks * 32 + quad * 8);
        int s0 = q0 - 64 + ks * 32 + quad * 8;
        s0 = iclamp(s0, 0, 2040);
#pragma unroll
        for (int dt = 0; dt < 4; ++dt) {
            const bf16x8 vf = *(const bf16x8*)(Vh + (size_t)(dt * 16 + lq) * 2048 + s0);
            oa[dt] = MFMA16(pf, vf, oa[dt]);
        }
    }

#pragma unroll
    for (int dt = 0; dt < 4; ++dt)
#pragma unroll
        for (int r = 0; r < 4; ++r)
            pw[(quad * 4 + r) * 72 + dt * 16 + lq] = f2bf(oa[dt][r] * rinv[r]);
    {
        const int row = lane >> 2, c0 = (lane & 3) * 16;
        uint4 v0 = *(const uint4*)(pw + row * 72 + c0);
        uint4 v1 = *(const uint4*)(pw + row * 72 + c0 + 8);
        unsigned short* dp = AO + (size_t)(b * 2048 + q0 + row) * 1024 + h * 64 + c0;
        *(uint4*)(dp) = v0;
        *(uint4*)(dp + 8) = v1;
    }
}

// ---------- kernel 4: output projection (M=4096, N=1024, K=1024) ----------
// 128x128 tile, 8 waves (2M x 4N), grid 8x32 = 256 blocks = 1/CU.
// Counted-vmcnt schedule: 2 phases/K-tile, depth-2 prefetch, vmcnt(4),
// setprio around MFMA. LDS: A 2x128x64 (32KB) + B 2x128x64 (32KB) = 64 KB.

#define STAGE_O(BO, KT) do {                                                   \
    gload16(gAo0 + (KT), lAo0 + (BO)); gload16(gAo1 + (KT), lAo1 + (BO));      \
    gload16(gBo0 + (KT), lBo0 + (BO)); gload16(gBo1 + (KT), lBo1 + (BO)); } while (0)

#define KTILE_O(AB, BB, BO, T) do {                                            \
    bf16x8 a00, a01, a10, a11, b00, b10, b01, b11;                             \
    b00 = *(const bf16x8*)((BB) + bRow + sw0);                                 \
    b10 = *(const bf16x8*)((BB) + bRow + sw1);                                 \
    b01 = *(const bf16x8*)((BB) + bRow + 1024 + sw0);                          \
    b11 = *(const bf16x8*)((BB) + bRow + 1024 + sw1);                          \
    a00 = *(const bf16x8*)((AB) + aRow + sw0);                                 \
    a01 = *(const bf16x8*)((AB) + aRow + sw1);                                 \
    a10 = *(const bf16x8*)((AB) + aRow + 1024 + sw0);                          \
    a11 = *(const bf16x8*)((AB) + aRow + 1024 + sw1);                          \
    QKV_BAR; QKV_LGKM0; QKV_SB0;                                               \
    QKV_PRIO1;                                                                 \
    acc[0][0]=MFMA16(a00,b00,acc[0][0]); acc[0][0]=MFMA16(a01,b10,acc[0][0]);  \
    acc[0][1]=MFMA16(a00,b01,acc[0][1]); acc[0][1]=MFMA16(a01,b11,acc[0][1]);  \
    acc[1][0]=MFMA16(a10,b00,acc[1][0]); acc[1][0]=MFMA16(a11,b10,acc[1][0]);  \
    acc[1][1]=MFMA16(a10,b01,acc[1][1]); acc[1][1]=MFMA16(a11,b11,acc[1][1]);  \
    QKV_PRIO0; QKV_BAR;                                                        \
    a00 = *(const bf16x8*)((AB) + aRow + 2048 + sw0);                          \
    a01 = *(const bf16x8*)((AB) + aRow + 2048 + sw1);                          \
    a10 = *(const bf16x8*)((AB) + aRow + 3072 + sw0);                          \
    a11 = *(const bf16x8*)((AB) + aRow + 3072 + sw1);                          \
    QKV_LGKM0; QKV_SB0; QKV_BAR;                                               \
    if ((T) < 14) STAGE_O((BO), (T) * 64 + 128);                               \
    QKV_PRIO1;                                                                 \
    acc[2][0]=MFMA16(a00,b00,acc[2][0]); acc[2][0]=MFMA16(a01,b10,acc[2][0]);  \
    acc[2][1]=MFMA16(a00,b01,acc[2][1]); acc[2][1]=MFMA16(a01,b11,acc[2][1]);  \
    acc[3][0]=MFMA16(a10,b00,acc[3][0]); acc[3][0]=MFMA16(a11,b10,acc[3][0]);  \
    acc[3][1]=MFMA16(a10,b01,acc[3][1]); acc[3][1]=MFMA16(a11,b11,acc[3][1]);  \
    QKV_PRIO0;                                                                 \
    if ((T) < 14)      { QKV_VM4; QKV_SB0; QKV_BAR; }                          \
    else if ((T) < 15) { QKV_VM0; QKV_SB0; QKV_BAR; }                          \
} while (0)

__global__ __launch_bounds__(512, 2) void gemm_out(const unsigned short* __restrict__ AO,
                                                   const unsigned short* __restrict__ Wot,
                                                   const float* __restrict__ bo,
                                                   float* __restrict__ out) {
    __shared__ __align__(16) unsigned short Asm[2 * 128 * 64];  // 32 KB
    __shared__ __align__(16) unsigned short Bsm[2 * 128 * 64];  // 32 KB
    const int tid = threadIdx.x, wave = tid >> 6, lane = tid & 63;
    const int lq = lane & 15, quad = lane >> 4;
    const int wr = wave >> 2, wc = wave & 3;
    const int m0 = blockIdx.y * 128, n0 = blockIdx.x * 128;

    f32x4 acc[4][2];
#pragma unroll
    for (int i = 0; i < 4; ++i)
#pragma unroll
        for (int j = 0; j < 2; ++j) acc[i][j] = f32x4{0.f, 0.f, 0.f, 0.f};

    float bi[2];
#pragma unroll
    for (int j = 0; j < 2; ++j) bi[j] = bo[n0 + wc * 32 + j * 16 + lq];

    const int r8 = lane >> 3, cs = lane & 7;
    const int gch = (cs ^ r8) * 8;
    const unsigned short* gAo0 = AO  + (size_t)(m0 +  0 + wave * 8 + r8) * 1024 + gch;
    const unsigned short* gAo1 = AO  + (size_t)(m0 + 64 + wave * 8 + r8) * 1024 + gch;
    const unsigned short* gBo0 = Wot + (size_t)(n0 +  0 + wave * 8 + r8) * 1024 + gch;
    const unsigned short* gBo1 = Wot + (size_t)(n0 + 64 + wave * 8 + r8) * 1024 + gch;
    unsigned short* lAo0 = Asm + ( 0 + wave * 8) * 64;
    unsigned short* lAo1 = Asm + (64 + wave * 8) * 64;
    unsigned short* lBo0 = Bsm + ( 0 + wave * 8) * 64;
    unsigned short* lBo1 = Bsm + (64 + wave * 8) * 64;

    const int sw0 = ((quad)     ^ (lq & 7)) * 8;
    const int sw1 = ((4 + quad) ^ (lq & 7)) * 8;
    const int aRow = (wr * 64 + lq) * 64;
    const int bRow = (wc * 32 + lq) * 64;

    // prologue: stage tiles 0 and 1; wait tile 0 (4 of tile 1 stay in flight)
    STAGE_O(0, 0);
    STAGE_O(8192, 64);
    QKV_VM4; QKV_SB0; QKV_BAR;

    for (int u = 0; u < 8; ++u) {
        const int t0 = u * 2;
        KTILE_O(Asm,        Bsm,        0,    t0);
        KTILE_O(Asm + 8192, Bsm + 8192, 8192, t0 + 1);
    }

    // epilogue: barrier, then f32 stride-33 LDS bounce -> 2x dwordx4 per lane
    __syncthreads();
    float* swf = (float*)Asm + wave * 528;     // 16 rows x 33 f32 per wave
    const int row = lane >> 2, c0 = (lane & 3) * 8;
    const size_t obase = (size_t)(m0 + wr * 64) * 1024 + n0 + wc * 32;
#pragma unroll
    for (int i = 0; i < 4; ++i) {
#pragma unroll
        for (int j = 0; j < 2; ++j)
#pragma unroll
            for (int r = 0; r < 4; ++r)
                swf[(quad * 4 + r) * 33 + j * 16 + lq] = acc[i][j][r] + bi[j];
        float4 v0, v1;
        v0.x = swf[row * 33 + c0 + 0]; v0.y = swf[row * 33 + c0 + 1];
        v0.z = swf[row * 33 + c0 + 2]; v0.w = swf[row * 33 + c0 + 3];
        v1.x = swf[row * 33 + c0 + 4]; v1.y = swf[row * 33 + c0 + 5];
        v1.z = swf[row * 33 + c0 + 6]; v1.w = swf[row * 33 + c0 + 7];
        float* op = out + obase + (size_t)(i * 16 + row) * 1024 + c0;
        *(float4*)(op) = v0;
        *(float4*)(op + 4) = v1;
    }
}

// ---------- host ----------
extern "C" void kernel_launch(void* const* d_in, const int* in_sizes, int n_in,
                              void* d_out, int out_size, void* d_ws, size_t ws_size,
                              hipStream_t stream) {
    const float* x  = (const float*)d_in[0];
    const float* Wq = (const float*)d_in[1];
    const float* bq = (const float*)d_in[2];
    const float* Wk = (const float*)d_in[3];
    const float* bk = (const float*)d_in[4];
    const float* Wv = (const float*)d_in[5];
    const float* bv = (const float*)d_in[6];
    const float* Wo = (const float*)d_in[7];
    const float* bo = (const float*)d_in[8];
    float* out = (float*)d_out;

    unsigned short* us = (unsigned short*)d_ws;
    const size_t MEG = 1048576;
    unsigned short* xb = us;                 // 4M bf16: x cast
    unsigned short* Wt = us + 4 * MEG;       // 4x1M bf16: W^T for Q,K,V,O
    unsigned short* Qb = us + 8 * MEG;       // [b,h,s,d]
    unsigned short* Kb = us + 12 * MEG;      // [b,h,s,d]
    unsigned short* Vt = us + 16 * MEG;      // [b,h,d,s]
    unsigned short* AO = us + 20 * MEG;      // [b,s,h*d]
    float* bcat = (float*)(us + 24 * MEG);   // 3072 f32

    prep_k<<<3084, 256, 0, stream>>>(x, Wq, Wk, Wv, Wo, bq, bk, bv, xb, Wt, bcat);
    gemm_qkv<<<dim3(16, 16), 512, 0, stream>>>(xb, Wt, bcat, Qb, Kb, Vt);
    attn_k<<<dim3(32, 16, 2), 256, 0, stream>>>(Qb, Kb, Vt, AO);
    gemm_out<<<dim3(8, 32), 512, 0, stream>>>(AO, Wt + 3 * MEG, bo, out);
}